// Round 17
// baseline (254.978 us; speedup 1.0000x reference)
//
#include <hip/hip_runtime.h>
#include <hip/hip_bf16.h>

#define BROWS 32768
#define CDIM 1000
#define CPAD 1024
#define HDIM 128
// Bijective LDS word swizzle (proven v6): XOR bits5-7 into bits2-4.
#define SWZ(w) ((w) ^ ((((w) >> 5) & 7) << 2))

typedef __attribute__((ext_vector_type(8))) short short8;
typedef __attribute__((ext_vector_type(4))) float f32x4;

__device__ inline unsigned short f2bf(float x) {
    unsigned int b = __float_as_uint(x);
    unsigned int r = (b + 0x7FFFu + ((b >> 16) & 1u)) >> 16;  // RNE
    return (unsigned short)r;
}
__device__ inline float bf2f(unsigned short u) {
    return __uint_as_float(((unsigned int)u) << 16);
}

// ---------------- prep: transpose weights to [N][K] bf16, zero-padded ----------------
__global__ __launch_bounds__(256) void k_prep(const float* __restrict__ W1,
                                              const float* __restrict__ W2,
                                              const float* __restrict__ W3,
                                              unsigned short* __restrict__ W1t,
                                              unsigned short* __restrict__ W2t,
                                              unsigned short* __restrict__ W3t) {
    const int idx = blockIdx.x * 256 + threadIdx.x;  // [0, 131072)
    {   // W1t[n][k], n<128, k<1024 ; W1 is [1000][128]
        const int n = idx >> 10, k = idx & 1023;
        W1t[idx] = (k < CDIM) ? f2bf(W1[(size_t)k * HDIM + n]) : (unsigned short)0;
    }
    {   // W3t[n][k], n<1024, k<128 ; W3 is [128][1000]
        const int n = idx >> 7, k = idx & 127;
        W3t[idx] = (n < CDIM) ? f2bf(W3[(size_t)k * CDIM + n]) : (unsigned short)0;
    }
    if (idx < 16384) {  // W2t[n][k], 128x128 ; W2 is [128][128]
        const int n = idx >> 7, k = idx & 127;
        W2t[idx] = f2bf(W2[(size_t)k * HDIM + n]);
    }
}

// ---------------- softmax: one wave per row, bf16 prob (padded 1024) + rstat ---------
__global__ __launch_bounds__(256) void k_softmax(const float* __restrict__ logits,
                                                 unsigned short* __restrict__ prob,
                                                 float2* __restrict__ rstat) {
    const int wv = threadIdx.x >> 6, lane = threadIdx.x & 63;
    const int row = (blockIdx.x << 2) + wv;
    const int base = lane << 4;
    const float* lrow = logits + (size_t)row * CDIM;
    float lg[16];
#pragma unroll
    for (int q = 0; q < 4; ++q) {
        const int c = base + (q << 2);
        if (c < CDIM) {
            const float4 v4 = *reinterpret_cast<const float4*>(lrow + c);
            lg[q * 4] = v4.x; lg[q * 4 + 1] = v4.y; lg[q * 4 + 2] = v4.z; lg[q * 4 + 3] = v4.w;
        } else {
            lg[q * 4] = lg[q * 4 + 1] = lg[q * 4 + 2] = lg[q * 4 + 3] = -INFINITY;
        }
    }
    float mx = lg[0];
#pragma unroll
    for (int e = 1; e < 16; ++e) mx = fmaxf(mx, lg[e]);
#pragma unroll
    for (int off = 32; off >= 1; off >>= 1) mx = fmaxf(mx, __shfl_xor(mx, off));
    float p[16], s = 0.f;
#pragma unroll
    for (int e = 0; e < 16; ++e) { p[e] = __expf(lg[e] - mx); s += p[e]; }
#pragma unroll
    for (int off = 32; off >= 1; off >>= 1) s += __shfl_xor(s, off);
    const float inv = 1.f / s;
    unsigned int w[8];
#pragma unroll
    for (int i = 0; i < 8; ++i) {
        const unsigned int lo = f2bf(p[2 * i] * inv);
        const unsigned int hi = f2bf(p[2 * i + 1] * inv);
        w[i] = lo | (hi << 16);
    }
    uint4 o0, o1;
    o0.x = w[0]; o0.y = w[1]; o0.z = w[2]; o0.w = w[3];
    o1.x = w[4]; o1.y = w[5]; o1.z = w[6]; o1.w = w[7];
    uint4* dst = reinterpret_cast<uint4*>(prob + (size_t)row * CPAD + base);
    dst[0] = o0; dst[1] = o1;
    if (lane == 0) rstat[row] = make_float2(mx, inv);
}

// ---------------- GEMM: C[M,N] = epi(A[M,K] @ Bt[N,K]^T + bias) ----------------------
template <int EPI>
__global__ __launch_bounds__(512) void k_gemm(const unsigned short* __restrict__ A, int lda,
                                              const unsigned short* __restrict__ Bt, int ldb,
                                              const float* __restrict__ bias,
                                              unsigned short* __restrict__ outp, int ldo,
                                              int K, int nlimit) {
    __shared__ uint4 As[128 * 8];
    __shared__ uint4 Bs[128 * 8];
    const int tid = threadIdx.x;
    const int bm = blockIdx.x, bn = blockIdx.y;
    const int lane = tid & 63, w = tid >> 6;
    const int wm = (w >> 1) << 5;
    const int wn = (w & 1) << 6;
    const int l15 = lane & 15, l4 = lane >> 4;
    f32x4 acc[2][4] = {};

    for (int k0 = 0; k0 < K; k0 += 64) {
        __syncthreads();
#pragma unroll
        for (int i = 0; i < 2; ++i) {
            const int cid = tid + (i << 9);
            const int r = cid >> 3, c = cid & 7;
            As[(r << 3) + (c ^ (r & 7))] =
                *reinterpret_cast<const uint4*>(A + (size_t)(bm * 128 + r) * lda + k0 + (c << 3));
            Bs[(r << 3) + (c ^ (r & 7))] =
                *reinterpret_cast<const uint4*>(Bt + (size_t)(bn * 128 + r) * ldb + k0 + (c << 3));
        }
        __syncthreads();
#pragma unroll
        for (int kk = 0; kk < 2; ++kk) {
            short8 a[2], b[4];
#pragma unroll
            for (int mf = 0; mf < 2; ++mf) {
                const int r = wm + (mf << 4) + l15;
                a[mf] = *reinterpret_cast<const short8*>(&As[(r << 3) + (((kk << 2) + l4) ^ (r & 7))]);
            }
#pragma unroll
            for (int nf = 0; nf < 4; ++nf) {
                const int r = wn + (nf << 4) + l15;
                b[nf] = *reinterpret_cast<const short8*>(&Bs[(r << 3) + (((kk << 2) + l4) ^ (r & 7))]);
            }
#pragma unroll
            for (int mf = 0; mf < 2; ++mf)
#pragma unroll
                for (int nf = 0; nf < 4; ++nf)
                    acc[mf][nf] = __builtin_amdgcn_mfma_f32_16x16x32_bf16(a[mf], b[nf], acc[mf][nf], 0, 0, 0);
        }
    }
#pragma unroll
    for (int mf = 0; mf < 2; ++mf) {
#pragma unroll
        for (int nf = 0; nf < 4; ++nf) {
            const int n = (bn << 7) + wn + (nf << 4) + l15;
            if (EPI == 1 && n >= nlimit) continue;
            const float bv = bias[n];
#pragma unroll
            for (int r = 0; r < 4; ++r) {
                const int m = (bm << 7) + wm + (mf << 4) + (l4 << 2) + r;
                float v = acc[mf][nf][r] + bv;
                if (EPI == 0) {
                    v = fmaxf(v, 0.f);
                } else {
                    if (n != nlimit - 1) v = 1.f / (1.f + __expf(-v));
                }
                outp[(size_t)m * ldo + n] = f2bf(v);
            }
        }
    }
}

// ================= ABLATION KERNELS (write reduced scratch; diagnose sortfinish) =====
// k_abA: loads(logits/cal/rstat) + exp + reduced write, x3 rows/wave. NO LDS.
//        -> 3x the memory+VALU floor of the sort kernel.
__global__ __launch_bounds__(256) void k_abA(const float* __restrict__ logits,
                                             const float2* __restrict__ rstat,
                                             const unsigned short* __restrict__ cal,
                                             float* __restrict__ red) {
    const int wv = threadIdx.x >> 6, lane = threadIdx.x & 63;
    const int base = lane << 4;
    for (int rr = 0; rr < 3; ++rr) {
        const int row = (blockIdx.x * 4 + wv) * 3 + rr;
        if (row >= BROWS) continue;
        const float* lrow = logits + (size_t)row * CDIM;
        float lg[16];
#pragma unroll
        for (int q = 0; q < 4; ++q) {
            const int c = base + (q << 2);
            if (c < CDIM) {
                const float4 v4 = *reinterpret_cast<const float4*>(lrow + c);
                lg[q * 4] = v4.x; lg[q * 4 + 1] = v4.y; lg[q * 4 + 2] = v4.z; lg[q * 4 + 3] = v4.w;
            } else {
                lg[q * 4] = lg[q * 4 + 1] = lg[q * 4 + 2] = lg[q * 4 + 3] = -INFINITY;
            }
        }
        const unsigned short* crow = cal + (size_t)row * CDIM + base;
        const uint4 c0 = *reinterpret_cast<const uint4*>(crow);
        const uint4 c1 = *reinterpret_cast<const uint4*>(crow + 8);
        const unsigned int cw[8] = {c0.x, c0.y, c0.z, c0.w, c1.x, c1.y, c1.z, c1.w};
        const float2 st = rstat[row];
        float acc = 0.f;
#pragma unroll
        for (int e = 0; e < 16; ++e) {
            const float pv = __expf(lg[e] - st.x) * st.y;
            const float cv = bf2f((unsigned short)((cw[e >> 1] >> ((e & 1) * 16)) & 0xFFFFu));
            acc += pv + cv;
        }
#pragma unroll
        for (int off = 32; off >= 1; off >>= 1) acc += __shfl_xor(acc, off);
        if (lane == 0) red[row] = acc;
    }
}

// k_abB: k_abA's work + zero-hist + ATOMIC pass + suffix-scan + rank read, x2 rows/wave.
//        Marginal over abA isolates the ranking machinery (the prime suspect).
__global__ __launch_bounds__(256) void k_abB(const float* __restrict__ logits,
                                             const float2* __restrict__ rstat,
                                             const unsigned short* __restrict__ cal,
                                             float* __restrict__ red) {
    __shared__ unsigned int shm[4 * 1024];
    const int wv = threadIdx.x >> 6, lane = threadIdx.x & 63;
    unsigned int* sm = &shm[wv << 10];
    const int base = lane << 4;
    int cb[4];
#pragma unroll
    for (int j = 0; j < 4; ++j) cb[j] = SWZ(base + (j << 2));

    for (int rr = 0; rr < 2; ++rr) {
        const int row = ((blockIdx.x << 2) + wv) * 2 + rr;
        const float* lrow = logits + (size_t)row * CDIM;
        float lg[16];
#pragma unroll
        for (int q = 0; q < 4; ++q) {
            const int c = base + (q << 2);
            if (c < CDIM) {
                const float4 v4 = *reinterpret_cast<const float4*>(lrow + c);
                lg[q * 4] = v4.x; lg[q * 4 + 1] = v4.y; lg[q * 4 + 2] = v4.z; lg[q * 4 + 3] = v4.w;
            } else {
                lg[q * 4] = lg[q * 4 + 1] = lg[q * 4 + 2] = lg[q * 4 + 3] = -INFINITY;
            }
        }
        const unsigned short* crow = cal + (size_t)row * CDIM + base;
        const uint4 c0 = *reinterpret_cast<const uint4*>(crow);
        const uint4 c1 = *reinterpret_cast<const uint4*>(crow + 8);
        const unsigned int cw[8] = {c0.x, c0.y, c0.z, c0.w, c1.x, c1.y, c1.z, c1.w};
        const float2 st = rstat[row];
        float p[16];
        float acc = 0.f;
#pragma unroll
        for (int e = 0; e < 16; ++e) {
            p[e] = __expf(lg[e] - st.x) * st.y;
            const float cv = bf2f((unsigned short)((cw[e >> 1] >> ((e & 1) * 16)) & 0xFFFFu));
            acc += p[e] + cv;
        }
        // zero histogram
        {
            uint4 z; z.x = 0; z.y = 0; z.z = 0; z.w = 0;
#pragma unroll
            for (int j = 0; j < 4; ++j) *reinterpret_cast<uint4*>(&sm[cb[j]]) = z;
        }
        // atomic pass
        unsigned int offv[16];
#pragma unroll
        for (int e = 0; e < 16; ++e) {
            const unsigned int key = __float_as_uint(p[e]) >> 20;
            offv[e] = (base + e < CDIM) ? atomicAdd(&sm[SWZ((int)key)], 1u) : 0u;
            acc += (float)offv[e];
        }
        // suffix-scan
        {
            unsigned int c16[16];
#pragma unroll
            for (int j = 0; j < 4; ++j) {
                const uint4 v4 = *reinterpret_cast<const uint4*>(&sm[cb[j]]);
                c16[4 * j] = v4.x; c16[4 * j + 1] = v4.y; c16[4 * j + 2] = v4.z; c16[4 * j + 3] = v4.w;
            }
            unsigned int lsum = 0;
#pragma unroll
            for (int e = 0; e < 16; ++e) lsum += c16[e];
            unsigned int suf = lsum;
#pragma unroll
            for (int off = 1; off < 64; off <<= 1) {
                const unsigned int u = __shfl_down(suf, off);
                if (lane + off < 64) suf += u;
            }
            unsigned int run = suf - lsum;
            unsigned int stv[16];
#pragma unroll
            for (int e = 15; e >= 0; --e) { stv[e] = run; run += c16[e]; }
#pragma unroll
            for (int j = 0; j < 4; ++j) {
                uint4 v4;
                v4.x = stv[4 * j]; v4.y = stv[4 * j + 1]; v4.z = stv[4 * j + 2]; v4.w = stv[4 * j + 3];
                *reinterpret_cast<uint4*>(&sm[cb[j]]) = v4;
            }
        }
        // rank read
#pragma unroll
        for (int e = 0; e < 16; ++e) {
            const unsigned int key = __float_as_uint(p[e]) >> 20;
            const int rk = (base + e < CDIM) ? (int)(sm[SWZ((int)key)] + offv[e]) : 1023;
            acc += (float)rk;
        }
#pragma unroll
        for (int off = 32; off >= 1; off >>= 1) acc += __shfl_xor(acc, off);
        if (lane == 0) red[row] = acc;
    }
}

// ---------------- sort + finish v7 (r15, best measured): 4 rows/wave, prefetch -------
__global__ __launch_bounds__(256) void k_sortfinish(const float* __restrict__ logits,
                                                    const float2* __restrict__ rstat,
                                                    const unsigned short* __restrict__ cal,
                                                    float* __restrict__ out) {
    __shared__ unsigned int shm[4 * 1024];
    const int wv = threadIdx.x >> 6, lane = threadIdx.x & 63;
    unsigned int* sm = &shm[wv << 10];
    const int base = lane << 4;
    const int row0 = (blockIdx.x << 4) + (wv << 2);

    int cb[4];
#pragma unroll
    for (int j = 0; j < 4; ++j) { const int wd = base + (j << 2); cb[j] = SWZ(wd); }

    float4 lgb[2][4]; uint4 c0b[2], c1b[2]; float2 stb[2];
    {
        const float* lrow = logits + (size_t)row0 * CDIM;
#pragma unroll
        for (int q = 0; q < 4; ++q) {
            const int c = base + (q << 2);
            lgb[0][q] = (c < CDIM) ? *reinterpret_cast<const float4*>(lrow + c)
                                   : make_float4(-INFINITY, -INFINITY, -INFINITY, -INFINITY);
        }
        const unsigned short* crow = cal + (size_t)row0 * CDIM + base;
        c0b[0] = *reinterpret_cast<const uint4*>(crow);
        c1b[0] = *reinterpret_cast<const uint4*>(crow + 8);
        stb[0] = rstat[row0];
    }

#pragma unroll
    for (int rr = 0; rr < 4; ++rr) {
        const int buf = rr & 1;
        const int grow = row0 + rr;

        if (rr < 3) {
            const int nrow = grow + 1;
            const float* lrow = logits + (size_t)nrow * CDIM;
#pragma unroll
            for (int q = 0; q < 4; ++q) {
                const int c = base + (q << 2);
                lgb[buf ^ 1][q] = (c < CDIM) ? *reinterpret_cast<const float4*>(lrow + c)
                                             : make_float4(-INFINITY, -INFINITY, -INFINITY, -INFINITY);
            }
            const unsigned short* crow = cal + (size_t)nrow * CDIM + base;
            c0b[buf ^ 1] = *reinterpret_cast<const uint4*>(crow);
            c1b[buf ^ 1] = *reinterpret_cast<const uint4*>(crow + 8);
            stb[buf ^ 1] = rstat[nrow];
        }

        float lg[16];
#pragma unroll
        for (int q = 0; q < 4; ++q) {
            lg[q * 4] = lgb[buf][q].x; lg[q * 4 + 1] = lgb[buf][q].y;
            lg[q * 4 + 2] = lgb[buf][q].z; lg[q * 4 + 3] = lgb[buf][q].w;
        }
        const unsigned int cw[8] = {c0b[buf].x, c0b[buf].y, c0b[buf].z, c0b[buf].w,
                                    c1b[buf].x, c1b[buf].y, c1b[buf].z, c1b[buf].w};
        const float mx = stb[buf].x, inv = stb[buf].y;

        {
            uint4 z; z.x = 0; z.y = 0; z.z = 0; z.w = 0;
#pragma unroll
            for (int j = 0; j < 4; ++j) *reinterpret_cast<uint4*>(&sm[cb[j]]) = z;
        }

        float p[16];
#pragma unroll
        for (int e = 0; e < 16; ++e) p[e] = __expf(lg[e] - mx) * inv;

        unsigned int offv[16]; int swk[16];
#pragma unroll
        for (int e = 0; e < 16; ++e) {
            const unsigned int key = __float_as_uint(p[e]) >> 20;
            swk[e] = SWZ((int)key);
            offv[e] = (base + e < CDIM) ? atomicAdd(&sm[swk[e]], 1u) : 0u;
        }

        {
            unsigned int c16[16];
#pragma unroll
            for (int j = 0; j < 4; ++j) {
                const uint4 v4 = *reinterpret_cast<const uint4*>(&sm[cb[j]]);
                c16[4 * j] = v4.x; c16[4 * j + 1] = v4.y; c16[4 * j + 2] = v4.z; c16[4 * j + 3] = v4.w;
            }
            unsigned int lsum = 0;
#pragma unroll
            for (int e = 0; e < 16; ++e) lsum += c16[e];
            unsigned int suf = lsum;
#pragma unroll
            for (int off = 1; off < 64; off <<= 1) {
                const unsigned int u = __shfl_down(suf, off);
                if (lane + off < 64) suf += u;
            }
            unsigned int run = suf - lsum;
            unsigned int stv[16];
#pragma unroll
            for (int e = 15; e >= 0; --e) { stv[e] = run; run += c16[e]; }
#pragma unroll
            for (int j = 0; j < 4; ++j) {
                uint4 v4;
                v4.x = stv[4 * j]; v4.y = stv[4 * j + 1]; v4.z = stv[4 * j + 2]; v4.w = stv[4 * j + 3];
                *reinterpret_cast<uint4*>(&sm[cb[j]]) = v4;
            }
        }

        int swr[16];
#pragma unroll
        for (int e = 0; e < 16; ++e) {
            const int rk = (base + e < CDIM) ? (int)(sm[swk[e]] + offv[e]) : 1023;
            swr[e] = SWZ(rk);
        }

#pragma unroll
        for (int e = 0; e < 16; ++e)
            if (base + e < CDIM) sm[swr[e]] = __float_as_uint(p[e]);

        float sp[16];
#pragma unroll
        for (int j = 0; j < 4; ++j) {
            const uint4 v4 = *reinterpret_cast<const uint4*>(&sm[cb[j]]);
            sp[4 * j] = __uint_as_float(v4.x); sp[4 * j + 1] = __uint_as_float(v4.y);
            sp[4 * j + 2] = __uint_as_float(v4.z); sp[4 * j + 3] = __uint_as_float(v4.w);
        }
        const float spn_next = __shfl_down(sp[0], 1);
        float v[16];
#pragma unroll
        for (int e = 0; e < 16; ++e) {
            const int r = base + e;
            const float cv = bf2f((unsigned short)((cw[e >> 1] >> ((e & 1) * 16)) & 0xFFFFu));
            const float spn = (e < 15) ? sp[e + 1] : spn_next;
            float val;
            if (r < CDIM - 1) val = (sp[e] - spn) * cv;
            else if (r == CDIM - 1) val = cv;
            else val = 0.f;
            v[e] = val;
        }
        float lsuf[16], run = 0.f;
#pragma unroll
        for (int e = 15; e >= 0; --e) { run += v[e]; lsuf[e] = run; }
        float pi = run;
#pragma unroll
        for (int off = 1; off < 64; off <<= 1) {
            const float u = __shfl_up(pi, off);
            if (lane >= off) pi += u;
        }
        const float tot = __shfl(pi, 63);
        const float after = tot - pi;

#pragma unroll
        for (int j = 0; j < 4; ++j) {
            uint4 v4;
            v4.x = __float_as_uint(lsuf[4 * j] + after);
            v4.y = __float_as_uint(lsuf[4 * j + 1] + after);
            v4.z = __float_as_uint(lsuf[4 * j + 2] + after);
            v4.w = __float_as_uint(lsuf[4 * j + 3] + after);
            *reinterpret_cast<uint4*>(&sm[cb[j]]) = v4;
        }
        float f[16];
#pragma unroll
        for (int e = 0; e < 16; ++e) f[e] = __uint_as_float(sm[swr[e]]);
#pragma unroll
        for (int q = 0; q < 4; ++q) {
            const int c = base + (q << 2);
            if (c < CDIM) {
                float4 o;
                o.x = lg[q * 4] + f[q * 4];
                o.y = lg[q * 4 + 1] + f[q * 4 + 1];
                o.z = lg[q * 4 + 2] + f[q * 4 + 2];
                o.w = lg[q * 4 + 3] + f[q * 4 + 3];
                *reinterpret_cast<float4*>(out + (size_t)grow * CDIM + c) = o;
            }
        }
    }
}

// ---------------- host ----------------
extern "C" void kernel_launch(void* const* d_in, const int* in_sizes, int n_in,
                              void* d_out, int out_size, void* d_ws, size_t ws_size,
                              hipStream_t stream) {
    const float* logits = (const float*)d_in[0];
    const float* W1 = (const float*)d_in[1];
    const float* b1 = (const float*)d_in[2];
    const float* W2 = (const float*)d_in[3];
    const float* b2 = (const float*)d_in[4];
    const float* W3 = (const float*)d_in[5];
    const float* b3 = (const float*)d_in[6];
    float* out = (float*)d_out;

    char* ws = (char*)d_ws;
    unsigned short* prob = (unsigned short*)ws;                 // 64 MB (CPAD stride)
    unsigned short* h12  = (unsigned short*)(ws + 67108864);    // 8 MB: h1 then h2 in-place
    float2*         rstat= (float2*)(ws + 75497472);            // 256 KB
    unsigned short* W1t  = (unsigned short*)(ws + 75759616);    // 256 KB
    unsigned short* W2t  = (unsigned short*)(ws + 76021760);    // 32 KB
    unsigned short* W3t  = (unsigned short*)(ws + 76054528);    // 256 KB
    float*          red  = (float*)(ws + 76316672);             // 128 KB -> 76.4 MB total
    unsigned short* cal  = prob;  // prob dead after gemm1; cal compact ldo=CDIM

    k_prep<<<512, 256, 0, stream>>>(W1, W2, W3, W1t, W2t, W3t);
    k_softmax<<<BROWS / 4, 256, 0, stream>>>(logits, prob, rstat);
    k_gemm<0><<<dim3(BROWS / 128, 1), 512, 0, stream>>>(prob, CPAD, W1t, CPAD, b1, h12, HDIM, CPAD, 0);
    k_gemm<0><<<dim3(BROWS / 128, 1), 512, 0, stream>>>(h12, HDIM, W2t, HDIM, b2, h12, HDIM, HDIM, 0);
    k_gemm<1><<<dim3(BROWS / 128, 8), 512, 0, stream>>>(h12, HDIM, W3t, HDIM, b3, cal, CDIM, HDIM, CDIM);
    k_sortfinish<<<BROWS / 16, 256, 0, stream>>>(logits, rstat, cal, out);
    // ---- ablation probes (scratch-only; diagnose sortfinish phase costs) ----
    k_abA<<<(BROWS + 11) / 12, 256, 0, stream>>>(logits, rstat, cal, red);   // 3 rows/wave
    k_abB<<<BROWS / 8, 256, 0, stream>>>(logits, rstat, cal, red);           // 2 rows/wave
}

// Round 18
// 176.763 us; speedup vs baseline: 1.4425x; 1.4425x over previous
//
#include <hip/hip_runtime.h>
#include <hip/hip_bf16.h>

#define BROWS 32768
#define CDIM 1000
#define CPAD 1024
#define HDIM 128
// Bijective LDS word swizzle (proven v6): XOR bits5-7 into bits2-4; keeps 4-word
// chunks contiguous (b128) and balances the 64B-lane-stride pattern across banks.
#define SWZ(w) ((w) ^ ((((w) >> 5) & 7) << 2))

typedef __attribute__((ext_vector_type(8))) short short8;
typedef __attribute__((ext_vector_type(4))) float f32x4;

__device__ inline unsigned short f2bf(float x) {
    unsigned int b = __float_as_uint(x);
    unsigned int r = (b + 0x7FFFu + ((b >> 16) & 1u)) >> 16;  // RNE
    return (unsigned short)r;
}
__device__ inline float bf2f(unsigned short u) {
    return __uint_as_float(((unsigned int)u) << 16);
}

// ---------------- prep: transpose weights to [N][K] bf16, zero-padded ----------------
__global__ __launch_bounds__(256) void k_prep(const float* __restrict__ W1,
                                              const float* __restrict__ W2,
                                              const float* __restrict__ W3,
                                              unsigned short* __restrict__ W1t,
                                              unsigned short* __restrict__ W2t,
                                              unsigned short* __restrict__ W3t) {
    const int idx = blockIdx.x * 256 + threadIdx.x;  // [0, 131072)
    {   // W1t[n][k], n<128, k<1024 ; W1 is [1000][128]
        const int n = idx >> 10, k = idx & 1023;
        W1t[idx] = (k < CDIM) ? f2bf(W1[(size_t)k * HDIM + n]) : (unsigned short)0;
    }
    {   // W3t[n][k], n<1024, k<128 ; W3 is [128][1000]
        const int n = idx >> 7, k = idx & 127;
        W3t[idx] = (n < CDIM) ? f2bf(W3[(size_t)k * CDIM + n]) : (unsigned short)0;
    }
    if (idx < 16384) {  // W2t[n][k], 128x128 ; W2 is [128][128]
        const int n = idx >> 7, k = idx & 127;
        W2t[idx] = f2bf(W2[(size_t)k * HDIM + n]);
    }
}

// ---------------- softmax: one wave per row, bf16 prob (padded 1024) + rstat ---------
__global__ __launch_bounds__(256) void k_softmax(const float* __restrict__ logits,
                                                 unsigned short* __restrict__ prob,
                                                 float2* __restrict__ rstat) {
    const int wv = threadIdx.x >> 6, lane = threadIdx.x & 63;
    const int row = (blockIdx.x << 2) + wv;
    const int base = lane << 4;
    const float* lrow = logits + (size_t)row * CDIM;
    float lg[16];
#pragma unroll
    for (int q = 0; q < 4; ++q) {
        const int c = base + (q << 2);
        if (c < CDIM) {
            const float4 v4 = *reinterpret_cast<const float4*>(lrow + c);
            lg[q * 4] = v4.x; lg[q * 4 + 1] = v4.y; lg[q * 4 + 2] = v4.z; lg[q * 4 + 3] = v4.w;
        } else {
            lg[q * 4] = lg[q * 4 + 1] = lg[q * 4 + 2] = lg[q * 4 + 3] = -INFINITY;
        }
    }
    float mx = lg[0];
#pragma unroll
    for (int e = 1; e < 16; ++e) mx = fmaxf(mx, lg[e]);
#pragma unroll
    for (int off = 32; off >= 1; off >>= 1) mx = fmaxf(mx, __shfl_xor(mx, off));
    float p[16], s = 0.f;
#pragma unroll
    for (int e = 0; e < 16; ++e) { p[e] = __expf(lg[e] - mx); s += p[e]; }
#pragma unroll
    for (int off = 32; off >= 1; off >>= 1) s += __shfl_xor(s, off);
    const float inv = 1.f / s;
    unsigned int w[8];
#pragma unroll
    for (int i = 0; i < 8; ++i) {
        const unsigned int lo = f2bf(p[2 * i] * inv);
        const unsigned int hi = f2bf(p[2 * i + 1] * inv);
        w[i] = lo | (hi << 16);
    }
    uint4 o0, o1;
    o0.x = w[0]; o0.y = w[1]; o0.z = w[2]; o0.w = w[3];
    o1.x = w[4]; o1.y = w[5]; o1.z = w[6]; o1.w = w[7];
    uint4* dst = reinterpret_cast<uint4*>(prob + (size_t)row * CPAD + base);
    dst[0] = o0; dst[1] = o1;
    if (lane == 0) rstat[row] = make_float2(mx, inv);   // bitwise-same stats for sortfinish
}

// ---------------- GEMM: C[M,N] = epi(A[M,K] @ Bt[N,K]^T + bias) ----------------------
// 512 threads = 8 waves (4m x 2n), block tile 128x128, BK=64, XOR-swizzled LDS chunks.
// EPI 0: relu(v + bias). EPI 1: sigmoid except col nlimit-1 raw; stores n < nlimit.
// In-place outp==A is safe per-128-row-block (barrier orders reads before writes).
template <int EPI>
__global__ __launch_bounds__(512) void k_gemm(const unsigned short* __restrict__ A, int lda,
                                              const unsigned short* __restrict__ Bt, int ldb,
                                              const float* __restrict__ bias,
                                              unsigned short* __restrict__ outp, int ldo,
                                              int K, int nlimit) {
    __shared__ uint4 As[128 * 8];
    __shared__ uint4 Bs[128 * 8];
    const int tid = threadIdx.x;
    const int bm = blockIdx.x, bn = blockIdx.y;
    const int lane = tid & 63, w = tid >> 6;
    const int wm = (w >> 1) << 5;
    const int wn = (w & 1) << 6;
    const int l15 = lane & 15, l4 = lane >> 4;
    f32x4 acc[2][4] = {};

    for (int k0 = 0; k0 < K; k0 += 64) {
        __syncthreads();
#pragma unroll
        for (int i = 0; i < 2; ++i) {
            const int cid = tid + (i << 9);
            const int r = cid >> 3, c = cid & 7;
            As[(r << 3) + (c ^ (r & 7))] =
                *reinterpret_cast<const uint4*>(A + (size_t)(bm * 128 + r) * lda + k0 + (c << 3));
            Bs[(r << 3) + (c ^ (r & 7))] =
                *reinterpret_cast<const uint4*>(Bt + (size_t)(bn * 128 + r) * ldb + k0 + (c << 3));
        }
        __syncthreads();
#pragma unroll
        for (int kk = 0; kk < 2; ++kk) {
            short8 a[2], b[4];
#pragma unroll
            for (int mf = 0; mf < 2; ++mf) {
                const int r = wm + (mf << 4) + l15;
                a[mf] = *reinterpret_cast<const short8*>(&As[(r << 3) + (((kk << 2) + l4) ^ (r & 7))]);
            }
#pragma unroll
            for (int nf = 0; nf < 4; ++nf) {
                const int r = wn + (nf << 4) + l15;
                b[nf] = *reinterpret_cast<const short8*>(&Bs[(r << 3) + (((kk << 2) + l4) ^ (r & 7))]);
            }
#pragma unroll
            for (int mf = 0; mf < 2; ++mf)
#pragma unroll
                for (int nf = 0; nf < 4; ++nf)
                    acc[mf][nf] = __builtin_amdgcn_mfma_f32_16x16x32_bf16(a[mf], b[nf], acc[mf][nf], 0, 0, 0);
        }
    }
#pragma unroll
    for (int mf = 0; mf < 2; ++mf) {
#pragma unroll
        for (int nf = 0; nf < 4; ++nf) {
            const int n = (bn << 7) + wn + (nf << 4) + l15;
            if (EPI == 1 && n >= nlimit) continue;   // compact output: skip pad cols
            const float bv = bias[n];
#pragma unroll
            for (int r = 0; r < 4; ++r) {
                const int m = (bm << 7) + wm + (mf << 4) + (l4 << 2) + r;
                float v = acc[mf][nf][r] + bv;
                if (EPI == 0) {
                    v = fmaxf(v, 0.f);
                } else {
                    if (n != nlimit - 1) v = 1.f / (1.f + __expf(-v));
                }
                outp[(size_t)m * ldo + n] = f2bf(v);
            }
        }
    }
}

// ---------------- sort + finish v7 (best measured): 4 rows/wave, prefetch ------------
// Per row: 11-bit-key counting sort (single atomic pass -> stable offset; suffix-scan;
// rank = start[key]+offset), scatter probs, blocked read, diffs*cal, suffix sum,
// gather by rank, out = logits + fitted. SWZ LDS throughout; zero barriers.
// r17 ablation: no phase group dominates (front half < 81 µs bound; machinery ~20 µs);
// kernel sits at its mixed memory/latency plateau (~2.9 TB/s, 80 µs).
__global__ __launch_bounds__(256) void k_sortfinish(const float* __restrict__ logits,
                                                    const float2* __restrict__ rstat,
                                                    const unsigned short* __restrict__ cal,
                                                    float* __restrict__ out) {
    __shared__ unsigned int shm[4 * 1024];
    const int wv = threadIdx.x >> 6, lane = threadIdx.x & 63;
    unsigned int* sm = &shm[wv << 10];
    const int base = lane << 4;
    const int row0 = (blockIdx.x << 4) + (wv << 2);   // wave owns rows row0..row0+3

    int cb[4];
#pragma unroll
    for (int j = 0; j < 4; ++j) { const int wd = base + (j << 2); cb[j] = SWZ(wd); }

    float4 lgb[2][4]; uint4 c0b[2], c1b[2]; float2 stb[2];
    {
        const float* lrow = logits + (size_t)row0 * CDIM;
#pragma unroll
        for (int q = 0; q < 4; ++q) {
            const int c = base + (q << 2);
            lgb[0][q] = (c < CDIM) ? *reinterpret_cast<const float4*>(lrow + c)
                                   : make_float4(-INFINITY, -INFINITY, -INFINITY, -INFINITY);
        }
        const unsigned short* crow = cal + (size_t)row0 * CDIM + base;
        c0b[0] = *reinterpret_cast<const uint4*>(crow);   // cols>=1000 overread: in-ws, unused
        c1b[0] = *reinterpret_cast<const uint4*>(crow + 8);
        stb[0] = rstat[row0];
    }

#pragma unroll
    for (int rr = 0; rr < 4; ++rr) {
        const int buf = rr & 1;
        const int grow = row0 + rr;

        if (rr < 3) {
            const int nrow = grow + 1;
            const float* lrow = logits + (size_t)nrow * CDIM;
#pragma unroll
            for (int q = 0; q < 4; ++q) {
                const int c = base + (q << 2);
                lgb[buf ^ 1][q] = (c < CDIM) ? *reinterpret_cast<const float4*>(lrow + c)
                                             : make_float4(-INFINITY, -INFINITY, -INFINITY, -INFINITY);
            }
            const unsigned short* crow = cal + (size_t)nrow * CDIM + base;
            c0b[buf ^ 1] = *reinterpret_cast<const uint4*>(crow);
            c1b[buf ^ 1] = *reinterpret_cast<const uint4*>(crow + 8);
            stb[buf ^ 1] = rstat[nrow];
        }

        float lg[16];
#pragma unroll
        for (int q = 0; q < 4; ++q) {
            lg[q * 4] = lgb[buf][q].x; lg[q * 4 + 1] = lgb[buf][q].y;
            lg[q * 4 + 2] = lgb[buf][q].z; lg[q * 4 + 3] = lgb[buf][q].w;
        }
        const unsigned int cw[8] = {c0b[buf].x, c0b[buf].y, c0b[buf].z, c0b[buf].w,
                                    c1b[buf].x, c1b[buf].y, c1b[buf].z, c1b[buf].w};
        const float mx = stb[buf].x, inv = stb[buf].y;

        {
            uint4 z; z.x = 0; z.y = 0; z.z = 0; z.w = 0;
#pragma unroll
            for (int j = 0; j < 4; ++j) *reinterpret_cast<uint4*>(&sm[cb[j]]) = z;
        }

        float p[16];
#pragma unroll
        for (int e = 0; e < 16; ++e) p[e] = __expf(lg[e] - mx) * inv;

        unsigned int offv[16]; int swk[16];
#pragma unroll
        for (int e = 0; e < 16; ++e) {
            const unsigned int key = __float_as_uint(p[e]) >> 20;  // 11-bit monotone, <=1016
            swk[e] = SWZ((int)key);
            offv[e] = (base + e < CDIM) ? atomicAdd(&sm[swk[e]], 1u) : 0u;
        }

        {
            unsigned int c16[16];
#pragma unroll
            for (int j = 0; j < 4; ++j) {
                const uint4 v4 = *reinterpret_cast<const uint4*>(&sm[cb[j]]);
                c16[4 * j] = v4.x; c16[4 * j + 1] = v4.y; c16[4 * j + 2] = v4.z; c16[4 * j + 3] = v4.w;
            }
            unsigned int lsum = 0;
#pragma unroll
            for (int e = 0; e < 16; ++e) lsum += c16[e];
            unsigned int suf = lsum;
#pragma unroll
            for (int off = 1; off < 64; off <<= 1) {
                const unsigned int u = __shfl_down(suf, off);
                if (lane + off < 64) suf += u;
            }
            unsigned int run = suf - lsum;
            unsigned int stv[16];
#pragma unroll
            for (int e = 15; e >= 0; --e) { stv[e] = run; run += c16[e]; }
#pragma unroll
            for (int j = 0; j < 4; ++j) {
                uint4 v4;
                v4.x = stv[4 * j]; v4.y = stv[4 * j + 1]; v4.z = stv[4 * j + 2]; v4.w = stv[4 * j + 3];
                *reinterpret_cast<uint4*>(&sm[cb[j]]) = v4;
            }
        }

        int swr[16];
#pragma unroll
        for (int e = 0; e < 16; ++e) {
            const int rk = (base + e < CDIM) ? (int)(sm[swk[e]] + offv[e]) : 1023;
            swr[e] = SWZ(rk);
        }

#pragma unroll
        for (int e = 0; e < 16; ++e)
            if (base + e < CDIM) sm[swr[e]] = __float_as_uint(p[e]);

        float sp[16];
#pragma unroll
        for (int j = 0; j < 4; ++j) {
            const uint4 v4 = *reinterpret_cast<const uint4*>(&sm[cb[j]]);
            sp[4 * j] = __uint_as_float(v4.x); sp[4 * j + 1] = __uint_as_float(v4.y);
            sp[4 * j + 2] = __uint_as_float(v4.z); sp[4 * j + 3] = __uint_as_float(v4.w);
        }
        const float spn_next = __shfl_down(sp[0], 1);
        float v[16];
#pragma unroll
        for (int e = 0; e < 16; ++e) {
            const int r = base + e;
            const float cv = bf2f((unsigned short)((cw[e >> 1] >> ((e & 1) * 16)) & 0xFFFFu));
            const float spn = (e < 15) ? sp[e + 1] : spn_next;
            float val;
            if (r < CDIM - 1) val = (sp[e] - spn) * cv;
            else if (r == CDIM - 1) val = cv;
            else val = 0.f;
            v[e] = val;
        }
        float lsuf[16], run = 0.f;
#pragma unroll
        for (int e = 15; e >= 0; --e) { run += v[e]; lsuf[e] = run; }
        float pi = run;
#pragma unroll
        for (int off = 1; off < 64; off <<= 1) {
            const float u = __shfl_up(pi, off);
            if (lane >= off) pi += u;
        }
        const float tot = __shfl(pi, 63);
        const float after = tot - pi;

#pragma unroll
        for (int j = 0; j < 4; ++j) {
            uint4 v4;
            v4.x = __float_as_uint(lsuf[4 * j] + after);
            v4.y = __float_as_uint(lsuf[4 * j + 1] + after);
            v4.z = __float_as_uint(lsuf[4 * j + 2] + after);
            v4.w = __float_as_uint(lsuf[4 * j + 3] + after);
            *reinterpret_cast<uint4*>(&sm[cb[j]]) = v4;
        }
        float f[16];
#pragma unroll
        for (int e = 0; e < 16; ++e) f[e] = __uint_as_float(sm[swr[e]]);
#pragma unroll
        for (int q = 0; q < 4; ++q) {
            const int c = base + (q << 2);
            if (c < CDIM) {
                float4 o;
                o.x = lg[q * 4] + f[q * 4];
                o.y = lg[q * 4 + 1] + f[q * 4 + 1];
                o.z = lg[q * 4 + 2] + f[q * 4 + 2];
                o.w = lg[q * 4 + 3] + f[q * 4 + 3];
                *reinterpret_cast<float4*>(out + (size_t)grow * CDIM + c) = o;
            }
        }
    }
}

// ---------------- host ----------------
extern "C" void kernel_launch(void* const* d_in, const int* in_sizes, int n_in,
                              void* d_out, int out_size, void* d_ws, size_t ws_size,
                              hipStream_t stream) {
    const float* logits = (const float*)d_in[0];
    const float* W1 = (const float*)d_in[1];
    const float* b1 = (const float*)d_in[2];
    const float* W2 = (const float*)d_in[3];
    const float* b2 = (const float*)d_in[4];
    const float* W3 = (const float*)d_in[5];
    const float* b3 = (const float*)d_in[6];
    float* out = (float*)d_out;

    char* ws = (char*)d_ws;
    unsigned short* prob = (unsigned short*)ws;                 // 64 MB (CPAD stride)
    unsigned short* h12  = (unsigned short*)(ws + 67108864);    // 8 MB: h1, then h2 in-place
    float2*         rstat= (float2*)(ws + 75497472);            // 256 KB
    unsigned short* W1t  = (unsigned short*)(ws + 75759616);    // 256 KB
    unsigned short* W2t  = (unsigned short*)(ws + 76021760);    // 32 KB
    unsigned short* W3t  = (unsigned short*)(ws + 76054528);    // 256 KB -> 76.3 MB total
    unsigned short* cal  = prob;  // prob dead after gemm1; cal compact ldo=CDIM

    k_prep<<<512, 256, 0, stream>>>(W1, W2, W3, W1t, W2t, W3t);
    k_softmax<<<BROWS / 4, 256, 0, stream>>>(logits, prob, rstat);
    k_gemm<0><<<dim3(BROWS / 128, 1), 512, 0, stream>>>(prob, CPAD, W1t, CPAD, b1, h12, HDIM, CPAD, 0);
    k_gemm<0><<<dim3(BROWS / 128, 1), 512, 0, stream>>>(h12, HDIM, W2t, HDIM, b2, h12, HDIM, HDIM, 0);
    k_gemm<1><<<dim3(BROWS / 128, 8), 512, 0, stream>>>(h12, HDIM, W3t, HDIM, b3, cal, CDIM, HDIM, CDIM);
    k_sortfinish<<<BROWS / 16, 256, 0, stream>>>(logits, rstat, cal, out);
}